// Round 5
// baseline (374.295 us; speedup 1.0000x reference)
//
#include <hip/hip_runtime.h>
#include <math.h>

#define BN 8
#define C1 256
#define C2 128
#define WD 512

typedef float  f32x4  __attribute__((ext_vector_type(4)));
typedef short  bf16x8 __attribute__((ext_vector_type(8)));
typedef unsigned short ushort_t;
typedef ushort_t us8 __attribute__((ext_vector_type(8)));
typedef ushort_t us4 __attribute__((ext_vector_type(4)));
typedef unsigned int u32;

__device__ __forceinline__ int clampi(int v, int lo, int hi) {
    return v < lo ? lo : (v > hi ? hi : v);
}
__device__ __forceinline__ float bf2f(ushort_t u) {
    return __uint_as_float(((unsigned int)u) << 16);
}
__device__ __forceinline__ ushort_t f2bf(float f) {
    unsigned int u = __float_as_uint(f);
    u = (u + 0x7fff + ((u >> 16) & 1)) >> 16;   // RNE
    return (ushort_t)u;
}

// ---------------- affine (wave-per-output): s1, s2, n1, n2 ----------------
__global__ __launch_bounds__(256)
void affine_kernel(const float* __restrict__ w, const float* __restrict__ n,
                   const float* __restrict__ A1w, const float* __restrict__ A1b,
                   const float* __restrict__ B1w, const float* __restrict__ B1b,
                   const float* __restrict__ A2w, const float* __restrict__ A2b,
                   const float* __restrict__ B2w, const float* __restrict__ B2b,
                   float* __restrict__ s1, float* __restrict__ s2,
                   float* __restrict__ n1, float* __restrict__ n2) {
    int tid = threadIdx.x;
    int gw = blockIdx.x * 4 + (tid >> 6);
    int lane = tid & 63;
    if (gw >= BN * 896) return;
    int b = gw / 896;
    int j = gw % 896;
    const float* vec; const float* M; const float* bias; float* out; int o;
    if (j < 256)      { o = j;       vec = w + b * WD; M = A1w; bias = A1b; out = s1 + b * 256; }
    else if (j < 512) { o = j - 256; vec = w + b * WD; M = A2w; bias = A2b; out = s2 + b * 256; }
    else if (j < 768) { o = j - 512; vec = n + b * WD; M = B1w; bias = B1b; out = n1 + b * 256; }
    else              { o = j - 768; vec = n + b * WD; M = B2w; bias = B2b; out = n2 + b * 128; }
    const float* row = M + (size_t)o * WD;
    int k0 = lane * 8;
    float4 v0 = *(const float4*)(vec + k0), v1 = *(const float4*)(vec + k0 + 4);
    float4 r0 = *(const float4*)(row + k0), r1 = *(const float4*)(row + k0 + 4);
    float acc = v0.x*r0.x + v0.y*r0.y + v0.z*r0.z + v0.w*r0.w
              + v1.x*r1.x + v1.y*r1.y + v1.z*r1.z + v1.w*r1.w;
    #pragma unroll
    for (int m = 1; m < 64; m <<= 1) acc += __shfl_xor(acc, m, 64);
    if (lane == 0) out[o] = acc + bias[o];
}

// ---------------- demod (wave-per-output) ----------------
__global__ __launch_bounds__(256)
void demod_kernel(const float* __restrict__ cw1, const float* __restrict__ cw2,
                  const float* __restrict__ s1, const float* __restrict__ s2,
                  float* __restrict__ d1, float* __restrict__ d2) {
    int tid = threadIdx.x;
    int gw = blockIdx.x * 4 + (tid >> 6);
    int lane = tid & 63;
    if (gw >= BN * 384) return;
    int b = gw / 384;
    int j = gw % 384;
    const float* wbase; const float* s; float* dout; int o;
    if (j < 256) { o = j;       wbase = cw1; s = s1 + b * 256; dout = d1 + b * 256; }
    else         { o = j - 256; wbase = cw2; s = s2 + b * 256; dout = d2 + b * 128; }
    float acc = 0.f;
    #pragma unroll
    for (int i = 0; i < 4; i++) {
        int ic = lane * 4 + i;
        float sv = s[ic]; sv *= sv;
        const float* wk = wbase + ((size_t)o * 256 + ic) * 9;
        float t = 0.f;
        #pragma unroll
        for (int k = 0; k < 9; k++) t += wk[k] * wk[k];
        acc += t * sv;
    }
    #pragma unroll
    for (int m = 1; m < 64; m <<= 1) acc += __shfl_xor(acc, m, 64);
    if (lane == 0) dout[o] = rsqrtf(acc + 1e-5f);
}

// ---- weight prep -> bf16, BOTH flat: wT[tap][oc][256 ic] (direct A-frag lane loads) ----
__global__ __launch_bounds__(256)
void wprep_kernel(const float* __restrict__ cw1, const float* __restrict__ cw2,
                  ushort_t* __restrict__ wT1, ushort_t* __restrict__ wT2) {
    int idx = blockIdx.x * 256 + threadIdx.x;
    if (idx < 9 * 256 * 256) {
        int tap = idx >> 16;
        int oc = (idx >> 8) & 255;
        int ic = idx & 255;
        wT1[idx] = f2bf(cw1[((size_t)(oc * 256 + ic)) * 9 + tap]);
    } else if (idx < 9 * 256 * 256 + 9 * 128 * 256) {
        int e = idx - 9 * 256 * 256;
        int tap = e >> 15;
        int oc = (e >> 8) & 127;
        int ic = e & 255;
        wT2[e] = f2bf(cw2[((size_t)(oc * 256 + ic)) * 9 + tap]);
    }
}

// -------- xprep: x[b][ic][y][x] f32 -> xTp[b][64*64][256] bf16 (UNPADDED), styles folded --------
__global__ __launch_bounds__(512)
void xprep_kernel(const float* __restrict__ x, const float* __restrict__ s1,
                  ushort_t* __restrict__ xTp) {
    int tid = threadIdx.x;
    int b = blockIdx.y;
    int px_lin = blockIdx.x * 16 + (tid >> 5);
    int ic8 = tid & 31;
    const float* xb = x + (((size_t)b * C1) << 12) + px_lin;
    float4 slo = *(const float4*)(s1 + b * 256 + ic8 * 8);
    float4 shi = *(const float4*)(s1 + b * 256 + ic8 * 8 + 4);
    float sv[8] = {slo.x, slo.y, slo.z, slo.w, shi.x, shi.y, shi.z, shi.w};
    us8 h;
    #pragma unroll
    for (int j = 0; j < 8; j++) {
        float v = xb[((size_t)(ic8 * 8 + j)) << 12];
        h[j] = f2bf(v * sv[j]);
    }
    *(us8*)(xTp + ((size_t)b << 20) + (size_t)px_lin * 256 + ic8 * 8) = h;
}

// -------- upsample: y1T[b][64*64][256] -> y1up[b][128*128][256] (UNPADDED), *s2 folded --------
__global__ __launch_bounds__(256)
void upsample_kernel(const ushort_t* __restrict__ y1T, const float* __restrict__ s2,
                     ushort_t* __restrict__ y1up) {
    int flat = blockIdx.x * 256 + threadIdx.x;
    int b = blockIdx.y;
    int ic8 = flat & 31;
    int pxl = flat >> 5;
    int ux = pxl & 127, uy = pxl >> 7;
    int jyA; float wyA;
    if (uy & 1) { jyA = uy >> 1;       wyA = 0.75f; }
    else        { jyA = (uy >> 1) - 1; wyA = 0.25f; }
    int jxA; float wxA;
    if (ux & 1) { jxA = ux >> 1;       wxA = 0.75f; }
    else        { jxA = (ux >> 1) - 1; wxA = 0.25f; }
    int yA = clampi(jyA, 0, 63), yB = clampi(jyA + 1, 0, 63);
    int xA = clampi(jxA, 0, 63), xB = clampi(jxA + 1, 0, 63);
    float wyB = 1.f - wyA, wxB = 1.f - wxA;
    const ushort_t* yb = y1T + (((size_t)b) << 20) + ic8 * 8;
    us8 qAA = *(const us8*)(yb + (size_t)(yA * 64 + xA) * 256);
    us8 qAB = *(const us8*)(yb + (size_t)(yA * 64 + xB) * 256);
    us8 qBA = *(const us8*)(yb + (size_t)(yB * 64 + xA) * 256);
    us8 qBB = *(const us8*)(yb + (size_t)(yB * 64 + xB) * 256);
    float4 slo = *(const float4*)(s2 + b * 256 + ic8 * 8);
    float4 shi = *(const float4*)(s2 + b * 256 + ic8 * 8 + 4);
    float sv[8] = {slo.x, slo.y, slo.z, slo.w, shi.x, shi.y, shi.z, shi.w};
    us8 h;
    #pragma unroll
    for (int j = 0; j < 8; j++) {
        float v = wyA * (wxA * bf2f(qAA[j]) + wxB * bf2f(qAB[j]))
                + wyB * (wxA * bf2f(qBA[j]) + wxB * bf2f(qBB[j]));
        h[j] = f2bf(v * sv[j]);
    }
    *(us8*)(y1up + ((size_t)b << 22) + (size_t)(uy * 128 + ux) * 256 + ic8 * 8) = h;
}

// =========== conv MFMA v5: high-occupancy, single-buffer act, weights in regs ===========
// Tile = 16 px wide x TILEH px tall, 64 oc per block; wave = 16 oc x (16*TILEH) px.
// LDS: SINGLE act buffer, 4 ic-quad planes [q][HALOH*18 px][8 ic] -> ~20.7 KB.
//   With VGPR<=128 (launch_bounds 256,4) this gives 4 blocks/CU; grids are sized to
//   exactly 4*256 = 1024 blocks -> one full residency round, no ragged tail
//   (the R2-R4 pipelines all lost to a 1024-on-3-resident tail at ~20% occupancy).
// Sync: R1's proven 2-barrier scheme {compute; barrier; STOREK; barrier}.
// Weights: wf[9] in VGPRs from flat wT[tap][oc][256ic]; wfN[9] prefetched one kc
//   ahead (R3-proven), lane mapping = exact mfma_16x16x32 A fragment.
template<int IW, int OCTOT, int TPR, int TILEH, bool IS_CONV2>
__global__ __launch_bounds__(256, 4)
void conv_mfma(const ushort_t* __restrict__ inp, const ushort_t* __restrict__ wT,
               const float* __restrict__ dmod, const float* __restrict__ nza,
               ushort_t* __restrict__ outT,
               const float* __restrict__ rgb_in, const float* __restrict__ rw,
               const float* __restrict__ rb, float* __restrict__ xout,
               float* __restrict__ rgbo) {
    constexpr int HALOH = TILEH + 2;
    constexpr int PXU   = HALOH * 18 * 4;          // staging units (8 ic each)
    constexpr int NSTG  = (PXU + 255) / 256;
    constexpr int ACTN  = 4 * HALOH * 18 * 8;      // ushorts in act buffer
    constexpr int NPX   = TILEH * 16;
    constexpr int OSN   = IS_CONV2 ? 0 : NPX * 80; // output-staging ushorts (conv1 only)
    constexpr int SMEMN = ACTN > OSN ? ACTN : OSN;
    __shared__ __align__(16) ushort_t smem[SMEMN];

    const int b = blockIdx.z, ocg = blockIdx.y, tile = blockIdx.x;
    const int ty0 = (tile / TPR) * TILEH, tx0 = (tile % TPR) * 16;
    const int tid = threadIdx.x, lane = tid & 63, wave = tid >> 6;
    const int col = lane & 15, quad = lane >> 4;

    const ushort_t* inb = inp + (size_t)b * IW * IW * 256;

    // staging descriptors (kc-invariant): global q-fastest (64B/px coalesced),
    // LDS plane-major [q][px]; halo/out-of-image -> zero-fill
    int actOff[NSTG]; bool actOk[NSTG]; int ldsOff[NSTG];
    #pragma unroll
    for (int c = 0; c < NSTG; c++) {
        int u = tid + 256 * c;
        int px_l = u >> 2, q = u & 3;
        int py = px_l / 18, pxx = px_l - py * 18;
        int gy = ty0 + py - 1, gx = tx0 + pxx - 1;
        bool ok = (u < PXU) && (gy >= 0) && (gy < IW) && (gx >= 0) && (gx < IW);
        actOk[c] = ok;
        actOff[c] = ok ? ((gy * IW + gx) * 256 + q * 8) : 0;
        ldsOff[c] = (q * (HALOH * 18) + px_l) * 8;
    }
    // weight lane addressing: oc = ocg*64 + wave*16 + col, ic = kc*32 + quad*8
    const ushort_t* wlane = wT + (size_t)(ocg * 64 + wave * 16 + col) * 256 + quad * 8;
    const int TAPSTR = OCTOT * 256;

    us8 aReg[NSTG];
    const us8 zer = (us8)0;
#define LOADK(KC) { \
    _Pragma("unroll") for (int c = 0; c < NSTG; c++) \
        aReg[c] = actOk[c] ? *(const us8*)(inb + actOff[c] + (KC) * 32) : zer; }
#define STOREK() { \
    _Pragma("unroll") for (int c = 0; c < NSTG; c++) { \
        int u = tid + 256 * c; \
        if (u < PXU) *(us8*)(smem + ldsOff[c]) = aReg[c]; } }

    f32x4 acc[TILEH];
    #pragma unroll
    for (int nt = 0; nt < TILEH; nt++) acc[nt] = (f32x4)(0.f);

    bf16x8 wf[9], wfN[9];
    LOADK(0);
    #pragma unroll
    for (int t = 0; t < 9; t++) wf[t] = *(const bf16x8*)(wlane + t * TAPSTR);
    STOREK();
    __syncthreads();

    const ushort_t* bbase = smem + (quad * (HALOH * 18) + col) * 8;

    for (int kc = 0; kc < 8; kc++) {
        // prefetch NEXT kc: act globals (oldest first), then weights
        if (kc < 7) {
            LOADK(kc + 1);
            #pragma unroll
            for (int t = 0; t < 9; t++)
                wfN[t] = *(const bf16x8*)(wlane + t * TAPSTR + (kc + 1) * 32);
        }
        // compute from act buffer (weights in regs; B-frags from LDS)
        #pragma unroll
        for (int h = 0; h < TILEH / 8; h++) {
            #pragma unroll
            for (int dx = 0; dx < 3; dx++) {
                bf16x8 bb[10];
                #pragma unroll
                for (int j = 0; j < 10; j++)
                    bb[j] = *(const bf16x8*)(bbase + ((h * 8 + j) * 18 + dx) * 8);
                #pragma unroll
                for (int dy = 0; dy < 3; dy++)
                    #pragma unroll
                    for (int nt = 0; nt < 8; nt++)
                        acc[h * 8 + nt] = __builtin_amdgcn_mfma_f32_16x16x32_bf16(
                            wf[dy * 3 + dx], bb[nt + dy], acc[h * 8 + nt], 0, 0, 0);
            }
        }
        __syncthreads();          // all reads of act buffer done
        if (kc < 7) STOREK();     // overwrite with next kc's tile
        __syncthreads();          // writes visible
        if (kc < 7) {
            #pragma unroll
            for (int t = 0; t < 9; t++) wf[t] = wfN[t];
        }
    }
#undef LOADK
#undef STOREK

    if constexpr (!IS_CONV2) {
        // stage output tile in LDS, then 128B-coalesced stores
        ushort_t* oS = smem;      // NPX px * 80 us
        const int ocl = wave * 16 + quad * 4;
        const int oc0 = ocg * 64 + ocl;
        float4 dv = *(const float4*)(dmod + b * OCTOT + oc0);
        float4 nv = *(const float4*)(nza + b * OCTOT + oc0);
        float dva[4] = {dv.x, dv.y, dv.z, dv.w};
        float nva[4] = {nv.x, nv.y, nv.z, nv.w};
        #pragma unroll
        for (int nt = 0; nt < TILEH; nt++) {
            int px = nt * 16 + col;
            us4 h;
            #pragma unroll
            for (int r = 0; r < 4; r++) {
                float t = acc[nt][r] * dva[r] + nva[r];
                t = (t >= 0.f) ? t : 0.1f * t;
                h[r] = f2bf(t);
            }
            *(us4*)(oS + px * 80 + ocl) = h;
        }
        __syncthreads();
        constexpr int NP = NPX * 8 / 256;
        #pragma unroll
        for (int p = 0; p < NP; p++) {
            int idx = tid + 256 * p;
            int px = idx >> 3, oc8 = idx & 7;
            us8 v = *(const us8*)(oS + px * 80 + oc8 * 8);
            int gy = ty0 + (px >> 4), gx = tx0 + (px & 15);
            *(us8*)(outT + ((size_t)b * IW * IW + gy * IW + gx) * 256 + ocg * 64 + oc8 * 8) = v;
        }
    } else {
        const int oc0 = ocg * 64 + wave * 16 + quad * 4;
        float4 dv = *(const float4*)(dmod + b * 128 + oc0);
        float4 nv = *(const float4*)(nza + b * 128 + oc0);
        float dva[4] = {dv.x, dv.y, dv.z, dv.w};
        float nva[4] = {nv.x, nv.y, nv.z, nv.w};
        float rwa[3][4];
        #pragma unroll
        for (int c = 0; c < 3; c++) {
            float4 rv = *(const float4*)(rw + c * 128 + oc0);
            rwa[c][0] = rv.x; rwa[c][1] = rv.y; rwa[c][2] = rv.z; rwa[c][3] = rv.w;
        }
        #pragma unroll
        for (int nt = 0; nt < TILEH; nt++) {
            int uy = ty0 + nt, ux = tx0 + col;
            float pc0 = 0.f, pc1 = 0.f, pc2 = 0.f;
            #pragma unroll
            for (int r = 0; r < 4; r++) {
                float t = acc[nt][r] * dva[r] + nva[r];
                t = (t >= 0.f) ? t : 0.1f * t;
                xout[(((size_t)b * 128 + oc0 + r) << 14) + (uy << 7) + ux] = t;
                pc0 += rwa[0][r] * t;
                pc1 += rwa[1][r] * t;
                pc2 += rwa[2][r] * t;
            }
            // reduce partial RGB across the 4 quads (same pixel) -> 1 atomic per wave
            pc0 += __shfl_xor(pc0, 16, 64); pc0 += __shfl_xor(pc0, 32, 64);
            pc1 += __shfl_xor(pc1, 16, 64); pc1 += __shfl_xor(pc1, 32, 64);
            pc2 += __shfl_xor(pc2, 16, 64); pc2 += __shfl_xor(pc2, 32, 64);
            if (quad == 0) {
                if (ocg == 0 && wave == 0) {
                    // residual + bias exactly once per pixel
                    int jyA; float wyA;
                    if (uy & 1) { jyA = uy >> 1;       wyA = 0.75f; }
                    else        { jyA = (uy >> 1) - 1; wyA = 0.25f; }
                    int jxA; float wxA;
                    if (ux & 1) { jxA = ux >> 1;       wxA = 0.75f; }
                    else        { jxA = (ux >> 1) - 1; wxA = 0.25f; }
                    int yA = clampi(jyA, 0, 63), yB = clampi(jyA + 1, 0, 63);
                    int xA = clampi(jxA, 0, 63), xB = clampi(jxA + 1, 0, 63);
                    float wyB = 1.f - wyA, wxB = 1.f - wxA;
                    const float* rp3 = rgb_in + (((size_t)b * 3) << 12);
                    #pragma unroll
                    for (int c = 0; c < 3; c++) {
                        const float* rc = rp3 + ((size_t)c << 12);
                        float up = wyA * (wxA * rc[(yA << 6) + xA] + wxB * rc[(yA << 6) + xB])
                                 + wyB * (wxA * rc[(yB << 6) + xA] + wxB * rc[(yB << 6) + xB]);
                        if (c == 0) pc0 += rb[0] + up;
                        else if (c == 1) pc1 += rb[1] + up;
                        else pc2 += rb[2] + up;
                    }
                }
                const float S = 0.70710678118654752f;
                atomicAdd(rgbo + (((size_t)b * 3 + 0) << 14) + (uy << 7) + ux, pc0 * S);
                atomicAdd(rgbo + (((size_t)b * 3 + 1) << 14) + (uy << 7) + ux, pc1 * S);
                atomicAdd(rgbo + (((size_t)b * 3 + 2) << 14) + (uy << 7) + ux, pc2 * S);
            }
        }
    }
}

extern "C" void kernel_launch(void* const* d_in, const int* in_sizes, int n_in,
                              void* d_out, int out_size, void* d_ws, size_t ws_size,
                              hipStream_t stream) {
    (void)in_sizes; (void)n_in; (void)out_size; (void)ws_size;
    const float* x     = (const float*)d_in[0];
    const float* w     = (const float*)d_in[1];
    const float* n     = (const float*)d_in[2];
    const float* rgb   = (const float*)d_in[3];
    const float* cw1   = (const float*)d_in[4];
    const float* A1w   = (const float*)d_in[5];
    const float* A1b   = (const float*)d_in[6];
    const float* B1w   = (const float*)d_in[7];
    const float* B1b   = (const float*)d_in[8];
    const float* cw2   = (const float*)d_in[9];
    const float* A2w   = (const float*)d_in[10];
    const float* A2b   = (const float*)d_in[11];
    const float* B2w   = (const float*)d_in[12];
    const float* B2b   = (const float*)d_in[13];
    const float* rgbw  = (const float*)d_in[14];
    const float* rgbb  = (const float*)d_in[15];

    char* ws = (char*)d_ws;
    float* s1 = (float*)(ws);
    float* s2 = (float*)(ws + 8192);
    float* d1 = (float*)(ws + 16384);
    float* d2 = (float*)(ws + 24576);
    float* n1 = (float*)(ws + 28672);
    float* n2 = (float*)(ws + 36864);
    ushort_t* wT1  = (ushort_t*)(ws + 40960);          // 1179648 B  [tap][256oc][256ic]
    ushort_t* wT2  = (ushort_t*)(ws + 1220608);        // 589824 B   [tap][128oc][256ic]
    ushort_t* xTp  = (ushort_t*)(ws + 1810432);        // 16777216 B [b][64*64][256]
    ushort_t* y1up = (ushort_t*)(ws + 18587648);       // 67108864 B [b][128*128][256]
    ushort_t* y1T  = (ushort_t*)(ws + 85696512);       // 16777216 B [b][64*64][256]

    float* xout = (float*)d_out;
    float* rgbo = xout + (size_t)BN * C2 * 128 * 128;

    hipMemsetAsync(rgbo, 0, (size_t)BN * 3 * 128 * 128 * 4, stream);

    affine_kernel<<<1792, 256, 0, stream>>>(w, n, A1w, A1b, B1w, B1b, A2w, A2b, B2w, B2b,
                                            s1, s2, n1, n2);
    demod_kernel<<<768, 256, 0, stream>>>(cw1, cw2, s1, s2, d1, d2);
    wprep_kernel<<<(9 * 256 * 256 + 9 * 128 * 256 + 255) / 256, 256, 0, stream>>>(cw1, cw2, wT1, wT2);
    xprep_kernel<<<dim3(256, BN), 512, 0, stream>>>(x, s1, xTp);
    // conv1: 64x64 out, 256 oc -> tiles 16x8 px, grid 32*4*8 = 1024 = 4 blocks/CU exactly
    conv_mfma<64, 256, 4, 8, false><<<dim3(32, 4, BN), 256, 0, stream>>>(
        xTp, wT1, d1, n1, y1T, nullptr, nullptr, nullptr, nullptr, nullptr);
    upsample_kernel<<<dim3(2048, BN), 256, 0, stream>>>(y1T, s2, y1up);
    // conv2: 128x128 out, 128 oc -> tiles 16x16 px, grid 64*2*8 = 1024 = 4 blocks/CU exactly
    conv_mfma<128, 128, 8, 16, true><<<dim3(64, 2, BN), 256, 0, stream>>>(
        y1up, wT2, d2, n2, nullptr, rgb, rgbw, rgbb, xout, rgbo);
}

// Round 7
// 257.814 us; speedup vs baseline: 1.4518x; 1.4518x over previous
//
#include <hip/hip_runtime.h>
#include <math.h>

#define BN 8
#define C1 256
#define C2 128
#define WD 512

typedef float  f32x4  __attribute__((ext_vector_type(4)));
typedef short  bf16x8 __attribute__((ext_vector_type(8)));
typedef unsigned short ushort_t;
typedef ushort_t us8 __attribute__((ext_vector_type(8)));
typedef ushort_t us4 __attribute__((ext_vector_type(4)));

__device__ __forceinline__ int clampi(int v, int lo, int hi) {
    return v < lo ? lo : (v > hi ? hi : v);
}
__device__ __forceinline__ float bf2f(ushort_t u) {
    return __uint_as_float(((unsigned int)u) << 16);
}
__device__ __forceinline__ ushort_t f2bf(float f) {
    unsigned int u = __float_as_uint(f);
    u = (u + 0x7fff + ((u >> 16) & 1)) >> 16;   // RNE
    return (ushort_t)u;
}

// ---------------- affine (wave-per-output): s1, s2, n1, n2 ----------------
__global__ __launch_bounds__(256)
void affine_kernel(const float* __restrict__ w, const float* __restrict__ n,
                   const float* __restrict__ A1w, const float* __restrict__ A1b,
                   const float* __restrict__ B1w, const float* __restrict__ B1b,
                   const float* __restrict__ A2w, const float* __restrict__ A2b,
                   const float* __restrict__ B2w, const float* __restrict__ B2b,
                   float* __restrict__ s1, float* __restrict__ s2,
                   float* __restrict__ n1, float* __restrict__ n2) {
    int tid = threadIdx.x;
    int gw = blockIdx.x * 4 + (tid >> 6);
    int lane = tid & 63;
    if (gw >= BN * 896) return;
    int b = gw / 896;
    int j = gw % 896;
    const float* vec; const float* M; const float* bias; float* out; int o;
    if (j < 256)      { o = j;       vec = w + b * WD; M = A1w; bias = A1b; out = s1 + b * 256; }
    else if (j < 512) { o = j - 256; vec = w + b * WD; M = A2w; bias = A2b; out = s2 + b * 256; }
    else if (j < 768) { o = j - 512; vec = n + b * WD; M = B1w; bias = B1b; out = n1 + b * 256; }
    else              { o = j - 768; vec = n + b * WD; M = B2w; bias = B2b; out = n2 + b * 128; }
    const float* row = M + (size_t)o * WD;
    int k0 = lane * 8;
    float4 v0 = *(const float4*)(vec + k0), v1 = *(const float4*)(vec + k0 + 4);
    float4 r0 = *(const float4*)(row + k0), r1 = *(const float4*)(row + k0 + 4);
    float acc = v0.x*r0.x + v0.y*r0.y + v0.z*r0.z + v0.w*r0.w
              + v1.x*r1.x + v1.y*r1.y + v1.z*r1.z + v1.w*r1.w;
    #pragma unroll
    for (int m = 1; m < 64; m <<= 1) acc += __shfl_xor(acc, m, 64);
    if (lane == 0) out[o] = acc + bias[o];
}

// ---------------- demod (wave-per-output) ----------------
__global__ __launch_bounds__(256)
void demod_kernel(const float* __restrict__ cw1, const float* __restrict__ cw2,
                  const float* __restrict__ s1, const float* __restrict__ s2,
                  float* __restrict__ d1, float* __restrict__ d2) {
    int tid = threadIdx.x;
    int gw = blockIdx.x * 4 + (tid >> 6);
    int lane = tid & 63;
    if (gw >= BN * 384) return;
    int b = gw / 384;
    int j = gw % 384;
    const float* wbase; const float* s; float* dout; int o;
    if (j < 256) { o = j;       wbase = cw1; s = s1 + b * 256; dout = d1 + b * 256; }
    else         { o = j - 256; wbase = cw2; s = s2 + b * 256; dout = d2 + b * 128; }
    float acc = 0.f;
    #pragma unroll
    for (int i = 0; i < 4; i++) {
        int ic = lane * 4 + i;
        float sv = s[ic]; sv *= sv;
        const float* wk = wbase + ((size_t)o * 256 + ic) * 9;
        float t = 0.f;
        #pragma unroll
        for (int k = 0; k < 9; k++) t += wk[k] * wk[k];
        acc += t * sv;
    }
    #pragma unroll
    for (int m = 1; m < 64; m <<= 1) acc += __shfl_xor(acc, m, 64);
    if (lane == 0) dout[o] = rsqrtf(acc + 1e-5f);
}

// ---- weight prep -> bf16, layout wT[kc][tap][oc][32ic] (chunked, as R1) ----
// Coalesced remap: thread = one (oc,ic) pair -> reads 9 contiguous f32 (36B),
// writes 9 x 2B that combine into 64B lines across the 32-thread ic-group.
__global__ __launch_bounds__(256)
void wprep_kernel(const float* __restrict__ cw1, const float* __restrict__ cw2,
                  ushort_t* __restrict__ wT1, ushort_t* __restrict__ wT2) {
    int idx = blockIdx.x * 256 + threadIdx.x;
    if (idx < 256 * 256) {
        int oc = idx >> 8, ic = idx & 255;
        int kc = ic >> 5, icw = ic & 31;
        const float* src = cw1 + ((size_t)(oc * 256 + ic)) * 9;
        #pragma unroll
        for (int tap = 0; tap < 9; tap++)
            wT1[((size_t)((kc * 9 + tap) * 256 + oc)) * 32 + icw] = f2bf(src[tap]);
    } else if (idx < 256 * 256 + 128 * 256) {
        int e = idx - 256 * 256;
        int oc = e >> 8, ic = e & 255;
        int kc = ic >> 5, icw = ic & 31;
        const float* src = cw2 + ((size_t)(oc * 256 + ic)) * 9;
        #pragma unroll
        for (int tap = 0; tap < 9; tap++)
            wT2[((size_t)((kc * 9 + tap) * 128 + oc)) * 32 + icw] = f2bf(src[tap]);
    }
}

// -------- xprep v2: LDS-transpose, coalesced both sides --------
// x[b][ic][4096 px] f32 -> xTp[b][px][256 ic] bf16, s1 folded.
// Block = 64 px x 256 ic. Phase 1: float4 reads along px (coalesced), scale, bf16,
// store to LDS tile [64 px][pitch 264]. Phase 2: us8 writes of [px][ic] (coalesced).
__global__ __launch_bounds__(256)
void xprep_kernel(const float* __restrict__ x, const float* __restrict__ s1,
                  ushort_t* __restrict__ xTp) {
    __shared__ ushort_t tile[64 * 264];
    int b = blockIdx.y;
    int px0 = blockIdx.x * 64;
    int t = threadIdx.x;
    int pxl = (t & 15) * 4;          // 0..60
    int icb = t >> 4;                // 0..15
    const float* xb = x + (((size_t)b * C1) << 12) + px0;
    #pragma unroll
    for (int p = 0; p < 16; p++) {
        int ic = p * 16 + icb;
        float sv = s1[b * 256 + ic];
        float4 v = *(const float4*)(xb + (((size_t)ic) << 12) + pxl);
        tile[(pxl + 0) * 264 + ic] = f2bf(v.x * sv);
        tile[(pxl + 1) * 264 + ic] = f2bf(v.y * sv);
        tile[(pxl + 2) * 264 + ic] = f2bf(v.z * sv);
        tile[(pxl + 3) * 264 + ic] = f2bf(v.w * sv);
    }
    __syncthreads();
    ushort_t* outb = xTp + ((size_t)b << 20) + (size_t)px0 * 256;
    #pragma unroll
    for (int p = 0; p < 8; p++) {
        int u = t + 256 * p;
        int px = u >> 5, w8 = u & 31;
        us8 v = *(const us8*)(tile + px * 264 + w8 * 8);
        *(us8*)(outb + (size_t)px * 256 + w8 * 8) = v;
    }
}

// -------- upsample: y1T[b][64*64][256] -> y1up[b][128*128][256] (UNPADDED), *s2 folded --------
__global__ __launch_bounds__(256)
void upsample_kernel(const ushort_t* __restrict__ y1T, const float* __restrict__ s2,
                     ushort_t* __restrict__ y1up) {
    int flat = blockIdx.x * 256 + threadIdx.x;
    int b = blockIdx.y;
    int ic8 = flat & 31;
    int pxl = flat >> 5;
    int ux = pxl & 127, uy = pxl >> 7;
    int jyA; float wyA;
    if (uy & 1) { jyA = uy >> 1;       wyA = 0.75f; }
    else        { jyA = (uy >> 1) - 1; wyA = 0.25f; }
    int jxA; float wxA;
    if (ux & 1) { jxA = ux >> 1;       wxA = 0.75f; }
    else        { jxA = (ux >> 1) - 1; wxA = 0.25f; }
    int yA = clampi(jyA, 0, 63), yB = clampi(jyA + 1, 0, 63);
    int xA = clampi(jxA, 0, 63), xB = clampi(jxA + 1, 0, 63);
    float wyB = 1.f - wyA, wxB = 1.f - wxA;
    const ushort_t* yb = y1T + (((size_t)b) << 20) + ic8 * 8;
    us8 qAA = *(const us8*)(yb + (size_t)(yA * 64 + xA) * 256);
    us8 qAB = *(const us8*)(yb + (size_t)(yA * 64 + xB) * 256);
    us8 qBA = *(const us8*)(yb + (size_t)(yB * 64 + xA) * 256);
    us8 qBB = *(const us8*)(yb + (size_t)(yB * 64 + xB) * 256);
    float4 slo = *(const float4*)(s2 + b * 256 + ic8 * 8);
    float4 shi = *(const float4*)(s2 + b * 256 + ic8 * 8 + 4);
    float sv[8] = {slo.x, slo.y, slo.z, slo.w, shi.x, shi.y, shi.z, shi.w};
    us8 h;
    #pragma unroll
    for (int j = 0; j < 8; j++) {
        float v = wyA * (wxA * bf2f(qAA[j]) + wxB * bf2f(qAB[j]))
                + wyB * (wxA * bf2f(qBA[j]) + wxB * bf2f(qBB[j]));
        h[j] = f2bf(v * sv[j]);
    }
    *(us8*)(y1up + ((size_t)b << 22) + (size_t)(uy * 128 + ux) * 256 + ic8 * 8) = h;
}

// =========== unified conv MFMA (exact R1 structure, 274us-proven): 64 oc x 16x16 px ===========
template<int IW, int OCTOT, int TPR, bool IS_CONV2>
__global__ __launch_bounds__(256, 2)
void conv_mfma(const ushort_t* __restrict__ inp, const ushort_t* __restrict__ wT,
               const float* __restrict__ dmod, const float* __restrict__ nza,
               ushort_t* __restrict__ outT,
               const float* __restrict__ rgb_in, const float* __restrict__ rw,
               const float* __restrict__ rb, float* __restrict__ xout,
               float* __restrict__ rgbo) {
    __shared__ __align__(16) ushort_t smem[28928];   // 57856 B total
    ushort_t* actS = smem;            // 10432 ushorts
    ushort_t* wS   = smem + 10432;    // 18496 ushorts

    const int b = blockIdx.z, ocg = blockIdx.y, tile = blockIdx.x;
    const int tyT = tile / TPR, txT = tile % TPR;
    const int ty0 = tyT * 16, tx0 = txT * 16;
    const int tid = threadIdx.x, lane = tid & 63, wave = tid >> 6;
    const int col = lane & 15, quad = lane >> 4;

    const ushort_t* inb = inp + (size_t)b * IW * IW * 256;

    int actOff[6]; bool actOk[6];
    #pragma unroll
    for (int i = 0; i < 6; i++) {
        int u = tid + 256 * i;
        int px_l = u >> 2, q = u & 3;
        int py = px_l / 18, pxx = px_l - py * 18;
        int gy = ty0 + py - 1, gx = tx0 + pxx - 1;
        bool ok = (u < 1296) && (gy >= 0) && (gy < IW) && (gx >= 0) && (gx < IW);
        actOk[i] = ok;
        actOff[i] = ok ? ((gy * IW + gx) * 256 + q * 8) : 0;
    }
    int wOff[9];
    #pragma unroll
    for (int i = 0; i < 9; i++) {
        int u = tid + 256 * i;
        int tap = u >> 8, oc = (u >> 2) & 63, q = u & 3;
        wOff[i] = (tap * OCTOT + ocg * 64 + oc) * 32 + q * 8;
    }
    const int KSTRIDE = 9 * OCTOT * 32;

    us8 aReg[6], wReg[9];
    const us8 zer = (us8)0;
#define LOADK(KC) { \
    _Pragma("unroll") for (int i = 0; i < 6; i++) \
        aReg[i] = actOk[i] ? *(const us8*)(inb + actOff[i] + (KC) * 32) : zer; \
    _Pragma("unroll") for (int i = 0; i < 9; i++) \
        wReg[i] = *(const us8*)(wT + wOff[i] + (KC) * KSTRIDE); }
#define STOREK() { \
    _Pragma("unroll") for (int i = 0; i < 6; i++) { \
        int u = tid + 256 * i; \
        if (u < 1296) *(us8*)(actS + (u & 3) * 2608 + (u >> 2) * 8) = aReg[i]; } \
    _Pragma("unroll") for (int i = 0; i < 9; i++) { \
        int u = tid + 256 * i; \
        *(us8*)(wS + (u & 3) * 4624 + (u >> 2) * 8) = wReg[i]; } }

    f32x4 acc[4][4];
    #pragma unroll
    for (int mt = 0; mt < 4; mt++)
        #pragma unroll
        for (int nt = 0; nt < 4; nt++) acc[mt][nt] = (f32x4)(0.f);

    LOADK(0);
    STOREK();
    __syncthreads();

    const ushort_t* bbase = actS + quad * 2608 + (72 * wave + col) * 8;
    const ushort_t* abase = wS + quad * 4624 + col * 8;

    for (int kc = 0; kc < 8; kc++) {
        if (kc < 7) LOADK(kc + 1);
        #pragma unroll
        for (int dx = 0; dx < 3; dx++) {
            bf16x8 bb[6];
            #pragma unroll
            for (int r = 0; r < 6; r++)
                bb[r] = *(const bf16x8*)(bbase + (r * 18 + dx) * 8);
            #pragma unroll
            for (int dy = 0; dy < 3; dy++) {
                const int tap = dy * 3 + dx;
                bf16x8 a[4];
                #pragma unroll
                for (int mt = 0; mt < 4; mt++)
                    a[mt] = *(const bf16x8*)(abase + (tap * 64 + mt * 16) * 8);
                #pragma unroll
                for (int mt = 0; mt < 4; mt++)
                    #pragma unroll
                    for (int nt = 0; nt < 4; nt++)
                        acc[mt][nt] = __builtin_amdgcn_mfma_f32_16x16x32_bf16(
                            a[mt], bb[nt + dy], acc[mt][nt], 0, 0, 0);
            }
        }
        __syncthreads();
        if (kc < 7) { STOREK(); }
        __syncthreads();
    }
#undef LOADK
#undef STOREK

    if constexpr (!IS_CONV2) {
        ushort_t* oS = smem;
        #pragma unroll
        for (int mt = 0; mt < 4; mt++) {
            int oc0 = ocg * 64 + mt * 16 + quad * 4;
            float4 dv = *(const float4*)(dmod + b * OCTOT + oc0);
            float4 nv = *(const float4*)(nza + b * OCTOT + oc0);
            float dva[4] = {dv.x, dv.y, dv.z, dv.w};
            float nva[4] = {nv.x, nv.y, nv.z, nv.w};
            #pragma unroll
            for (int nt = 0; nt < 4; nt++) {
                int px = (4 * wave + nt) * 16 + col;
                us4 h;
                #pragma unroll
                for (int r = 0; r < 4; r++) {
                    float t = acc[mt][nt][r] * dva[r] + nva[r];
                    t = (t >= 0.f) ? t : 0.1f * t;
                    h[r] = f2bf(t);
                }
                *(us4*)(oS + px * 80 + mt * 16 + quad * 4) = h;
            }
        }
        __syncthreads();
        #pragma unroll
        for (int p = 0; p < 8; p++) {
            int idx = tid + 256 * p;
            int px = idx >> 3, oc8 = idx & 7;
            us8 v = *(const us8*)(oS + px * 80 + oc8 * 8);
            int gy = ty0 + (px >> 4), gx = tx0 + (px & 15);
            *(us8*)(outT + ((size_t)b * IW * IW + gy * IW + gx) * 256 + ocg * 64 + oc8 * 8) = v;
        }
    } else {
        float dva[4][4], nva[4][4], rwa[3][4][4];
        #pragma unroll
        for (int mt = 0; mt < 4; mt++) {
            int oc0 = ocg * 64 + mt * 16 + quad * 4;
            float4 dv = *(const float4*)(dmod + b * 128 + oc0);
            float4 nv = *(const float4*)(nza + b * 128 + oc0);
            dva[mt][0] = dv.x; dva[mt][1] = dv.y; dva[mt][2] = dv.z; dva[mt][3] = dv.w;
            nva[mt][0] = nv.x; nva[mt][1] = nv.y; nva[mt][2] = nv.z; nva[mt][3] = nv.w;
            #pragma unroll
            for (int c = 0; c < 3; c++) {
                float4 rv = *(const float4*)(rw + c * 128 + oc0);
                rwa[c][mt][0] = rv.x; rwa[c][mt][1] = rv.y; rwa[c][mt][2] = rv.z; rwa[c][mt][3] = rv.w;
            }
        }
        #pragma unroll
        for (int nt = 0; nt < 4; nt++) {
            int uy = ty0 + 4 * wave + nt, ux = tx0 + col;
            float pc0 = 0.f, pc1 = 0.f, pc2 = 0.f;
            #pragma unroll
            for (int mt = 0; mt < 4; mt++) {
                int oc0 = ocg * 64 + mt * 16 + quad * 4;
                #pragma unroll
                for (int r = 0; r < 4; r++) {
                    float t = acc[mt][nt][r] * dva[mt][r] + nva[mt][r];
                    t = (t >= 0.f) ? t : 0.1f * t;
                    xout[(((size_t)b * 128 + oc0 + r) << 14) + (uy << 7) + ux] = t;
                    pc0 += rwa[0][mt][r] * t;
                    pc1 += rwa[1][mt][r] * t;
                    pc2 += rwa[2][mt][r] * t;
                }
            }
            // reduce partial RGB across the 4 quads (same pixel) -> 1 atomic per wave
            pc0 += __shfl_xor(pc0, 16, 64); pc0 += __shfl_xor(pc0, 32, 64);
            pc1 += __shfl_xor(pc1, 16, 64); pc1 += __shfl_xor(pc1, 32, 64);
            pc2 += __shfl_xor(pc2, 16, 64); pc2 += __shfl_xor(pc2, 32, 64);
            if (quad == 0) {
                if (ocg == 0) {
                    // residual + bias exactly once per pixel (each pixel owned by one wave)
                    int jyA; float wyA;
                    if (uy & 1) { jyA = uy >> 1;       wyA = 0.75f; }
                    else        { jyA = (uy >> 1) - 1; wyA = 0.25f; }
                    int jxA; float wxA;
                    if (ux & 1) { jxA = ux >> 1;       wxA = 0.75f; }
                    else        { jxA = (ux >> 1) - 1; wxA = 0.25f; }
                    int yA = clampi(jyA, 0, 63), yB = clampi(jyA + 1, 0, 63);
                    int xA = clampi(jxA, 0, 63), xB = clampi(jxA + 1, 0, 63);
                    float wyB = 1.f - wyA, wxB = 1.f - wxA;
                    const float* rp3 = rgb_in + (((size_t)b * 3) << 12);
                    #pragma unroll
                    for (int c = 0; c < 3; c++) {
                        const float* rc = rp3 + ((size_t)c << 12);
                        float up = wyA * (wxA * rc[(yA << 6) + xA] + wxB * rc[(yA << 6) + xB])
                                 + wyB * (wxA * rc[(yB << 6) + xA] + wxB * rc[(yB << 6) + xB]);
                        if (c == 0) pc0 += rb[0] + up;
                        else if (c == 1) pc1 += rb[1] + up;
                        else pc2 += rb[2] + up;
                    }
                }
                const float S = 0.70710678118654752f;
                atomicAdd(rgbo + (((size_t)b * 3 + 0) << 14) + (uy << 7) + ux, pc0 * S);
                atomicAdd(rgbo + (((size_t)b * 3 + 1) << 14) + (uy << 7) + ux, pc1 * S);
                atomicAdd(rgbo + (((size_t)b * 3 + 2) << 14) + (uy << 7) + ux, pc2 * S);
            }
        }
    }
}

extern "C" void kernel_launch(void* const* d_in, const int* in_sizes, int n_in,
                              void* d_out, int out_size, void* d_ws, size_t ws_size,
                              hipStream_t stream) {
    (void)in_sizes; (void)n_in; (void)out_size; (void)ws_size;
    const float* x     = (const float*)d_in[0];
    const float* w     = (const float*)d_in[1];
    const float* n     = (const float*)d_in[2];
    const float* rgb   = (const float*)d_in[3];
    const float* cw1   = (const float*)d_in[4];
    const float* A1w   = (const float*)d_in[5];
    const float* A1b   = (const float*)d_in[6];
    const float* B1w   = (const float*)d_in[7];
    const float* B1b   = (const float*)d_in[8];
    const float* cw2   = (const float*)d_in[9];
    const float* A2w   = (const float*)d_in[10];
    const float* A2b   = (const float*)d_in[11];
    const float* B2w   = (const float*)d_in[12];
    const float* B2b   = (const float*)d_in[13];
    const float* rgbw  = (const float*)d_in[14];
    const float* rgbb  = (const float*)d_in[15];

    char* ws = (char*)d_ws;
    float* s1 = (float*)(ws);
    float* s2 = (float*)(ws + 8192);
    float* d1 = (float*)(ws + 16384);
    float* d2 = (float*)(ws + 24576);
    float* n1 = (float*)(ws + 28672);
    float* n2 = (float*)(ws + 36864);
    ushort_t* wT1  = (ushort_t*)(ws + 40960);          // 1179648 B  [kc][tap][256oc][32ic]
    ushort_t* wT2  = (ushort_t*)(ws + 1220608);        // 589824 B   [kc][tap][128oc][32ic]
    ushort_t* xTp  = (ushort_t*)(ws + 1810432);        // 16777216 B [b][64*64][256]
    ushort_t* y1up = (ushort_t*)(ws + 18587648);       // 67108864 B [b][128*128][256]
    ushort_t* y1T  = (ushort_t*)(ws + 85696512);       // 16777216 B [b][64*64][256]

    float* xout = (float*)d_out;
    float* rgbo = xout + (size_t)BN * C2 * 128 * 128;

    hipMemsetAsync(rgbo, 0, (size_t)BN * 3 * 128 * 128 * 4, stream);

    affine_kernel<<<1792, 256, 0, stream>>>(w, n, A1w, A1b, B1w, B1b, A2w, A2b, B2w, B2b,
                                            s1, s2, n1, n2);
    demod_kernel<<<768, 256, 0, stream>>>(cw1, cw2, s1, s2, d1, d2);
    wprep_kernel<<<(256 * 256 + 128 * 256) / 256, 256, 0, stream>>>(cw1, cw2, wT1, wT2);
    xprep_kernel<<<dim3(64, BN), 256, 0, stream>>>(x, s1, xTp);
    conv_mfma<64, 256, 4, false><<<dim3(16, 4, BN), 256, 0, stream>>>(
        xTp, wT1, d1, n1, y1T, nullptr, nullptr, nullptr, nullptr, nullptr);
    upsample_kernel<<<dim3(2048, BN), 256, 0, stream>>>(y1T, s2, y1up);
    conv_mfma<128, 128, 8, true><<<dim3(64, 2, BN), 256, 0, stream>>>(
        y1up, wT2, d2, n2, nullptr, rgb, rgbw, rgbb, xout, rgbo);
}